// Round 1
// baseline (187.987 us; speedup 1.0000x reference)
//
#include <hip/hip_runtime.h>
#include <math.h>

#define N_RAYS 65536
#define LAMBDA_OPACITY 0.001f
#define LAMBDA_DISTORTION 0.001f

// native clang vector type — accepted by __builtin_nontemporal_load
typedef float f32x4 __attribute__((ext_vector_type(4)));

#define NB_PERRAY (N_RAYS / 256)   // 256 perray blocks, dispatched first
#define NB_DIST   (N_RAYS / 4)     // 16384 distortion blocks (4 waves, 1 ray/wave)

// ---------------------------------------------------------------------------
// DPP wave64 inclusive-add scan (canonical gfx9 sequence, all-VALU) —
// verified R5/R7/R10.
// ---------------------------------------------------------------------------
template <int CTRL, int ROW_MASK>
__device__ __forceinline__ float dpp_add(float x) {
    int s = __builtin_amdgcn_update_dpp(0, __float_as_int(x),
                                        CTRL, ROW_MASK, 0xf, false);
    return x + __int_as_float(s);
}

__device__ __forceinline__ float wave64_incl_scan(float x) {
    x = dpp_add<0x111, 0xf>(x);  // row_shr:1
    x = dpp_add<0x112, 0xf>(x);  // row_shr:2
    x = dpp_add<0x114, 0xf>(x);  // row_shr:4
    x = dpp_add<0x118, 0xf>(x);  // row_shr:8
    x = dpp_add<0x142, 0xa>(x);  // row_bcast:15 -> rows 1,3
    x = dpp_add<0x143, 0xc>(x);  // row_bcast:31 -> rows 2,3
    return x;
}

// ---------------------------------------------------------------------------
// R11 = R10 + BW-measurement probe.
// The probe issues a second, cold, full-size nontemporal read of
// ws/ts/deltas (ray ^ 32768) whose values are kept alive by an empty
// asm volatile (prevents DCE, rule #17) but never enter the math.
// Numerics are bit-identical to R10. The marginal dur_us delta measures
// achieved read BW for exactly our access pattern, and the enlarged
// kernel surfaces in the rocprof top-5 with its own counters.
// ---------------------------------------------------------------------------
__global__ __launch_bounds__(256)
void fused_kernel(
    const float* __restrict__ rgb_coarse,
    const float* __restrict__ rgb_fine,
    const float* __restrict__ rgb_target,
    const float* __restrict__ depth,
    const float* __restrict__ depth_target,
    const float* __restrict__ opacity,
    const float* __restrict__ ws,
    const float* __restrict__ deltas,
    const float* __restrict__ ts,
    const int*   __restrict__ rays_a,
    float* __restrict__ out)
{
    if (blockIdx.x < NB_PERRAY) {
        // ---------------- per-ray cheap terms ----------------
        const int r = blockIdx.x * 256 + threadIdx.x;

        const float rt0 = __builtin_nontemporal_load(rgb_target + r * 3 + 0);
        const float rt1 = __builtin_nontemporal_load(rgb_target + r * 3 + 1);
        const float rt2 = __builtin_nontemporal_load(rgb_target + r * 3 + 2);
        const float c0 = __builtin_nontemporal_load(rgb_coarse + r * 3 + 0) - rt0;
        const float c1 = __builtin_nontemporal_load(rgb_coarse + r * 3 + 1) - rt1;
        const float c2 = __builtin_nontemporal_load(rgb_coarse + r * 3 + 2) - rt2;
        const float f0 = __builtin_nontemporal_load(rgb_fine + r * 3 + 0) - rt0;
        const float f1 = __builtin_nontemporal_load(rgb_fine + r * 3 + 1) - rt1;
        const float f2 = __builtin_nontemporal_load(rgb_fine + r * 3 + 2) - rt2;

        out[r] = (c0 * c0 + c1 * c1 + c2 * c2) * (1.f / 3.f)
               + (f0 * f0 + f1 * f1 + f2 * f2) * (1.f / 3.f);

        out[N_RAYS + r] = fabsf(__builtin_nontemporal_load(depth + r)
                              - __builtin_nontemporal_load(depth_target + r));

        const float o = __builtin_nontemporal_load(opacity + r) + 1e-10f;
        out[2 * N_RAYS + r] = LAMBDA_OPACITY * (-o * logf(o));
        return;
    }

    // ---------------- distortion (R10 winner) ----------------
    const int lane = threadIdx.x & 63;
    const int ray  = (blockIdx.x - NB_PERRAY) * 4 + (threadIdx.x >> 6);

    // speculative nontemporal data loads (identity layout)
    f32x4 vw = {0.f, 0.f, 0.f, 0.f};
    f32x4 vt = {0.f, 0.f, 0.f, 0.f};
    f32x4 vd = {0.f, 0.f, 0.f, 0.f};
    if (lane < 48) {
        const int sp = 192 * ray + 4 * lane;
        vw = __builtin_nontemporal_load((const f32x4*)(ws     + sp));
        vt = __builtin_nontemporal_load((const f32x4*)(ts     + sp));
        vd = __builtin_nontemporal_load((const f32x4*)(deltas + sp));
    }

    // meta load, independent of the data loads -> same round trip
    const int out_ray = rays_a[ray * 3 + 0];
    const int start   = rays_a[ray * 3 + 1];
    const int count   = rays_a[ray * 3 + 2];

    // ---- R11 probe: second cold read of the full distortion set ----
    // ray^32768 keeps addresses in-bounds and globally covers every byte
    // exactly once more. Values never used; kept live at kernel end.
    f32x4 pw = {0.f, 0.f, 0.f, 0.f};
    f32x4 pt = {0.f, 0.f, 0.f, 0.f};
    f32x4 pd = {0.f, 0.f, 0.f, 0.f};
    {
        const int ray2 = ray ^ 32768;
        if (lane < 48) {
            const int sp2 = 192 * ray2 + 4 * lane;
            pw = __builtin_nontemporal_load((const f32x4*)(ws     + sp2));
            pt = __builtin_nontemporal_load((const f32x4*)(ts     + sp2));
            pd = __builtin_nontemporal_load((const f32x4*)(deltas + sp2));
        }
    }

    __builtin_amdgcn_sched_barrier(0);

    float w[4] = {0.f, 0.f, 0.f, 0.f};
    float t[4] = {0.f, 0.f, 0.f, 0.f};
    float d[4] = {0.f, 0.f, 0.f, 0.f};

    if (start == 192 * ray && count == 192) {
        if (lane < 48) {
            w[0]=vw.x; w[1]=vw.y; w[2]=vw.z; w[3]=vw.w;
            t[0]=vt.x; t[1]=vt.y; t[2]=vt.z; t[3]=vt.w;
            d[0]=vd.x; d[1]=vd.y; d[2]=vd.z; d[3]=vd.w;
        }
    } else {
        // generic fallback: any start/count, guarded scalar loads
        #pragma unroll
        for (int e = 0; e < 4; ++e) {
            const int p  = 4 * lane + e;
            const bool ok = p < count;
            w[e] = ok ? ws[start + p]     : 0.f;
            t[e] = ok ? ts[start + p]     : 0.f;
            d[e] = ok ? deltas[start + p] : 0.f;
        }
    }

    // per-lane quad totals
    const float wt0 = w[0] * t[0], wt1 = w[1] * t[1];
    const float wt2 = w[2] * t[2], wt3 = w[3] * t[3];
    const float lw  = (w[0] + w[1]) + (w[2] + w[3]);
    const float lwt = (wt0 + wt1) + (wt2 + wt3);

    // DPP inclusive scans over quad totals (two independent chains)
    const float iw  = wave64_incl_scan(lw);
    const float iwt = wave64_incl_scan(lwt);

    // exclusive base for this quad
    float e_w  = iw  - lw;
    float e_wt = iwt - lwt;

    // lane-local sequential exclusive accumulation over the 4 samples
    float acc = 0.f;
    #pragma unroll
    for (int e = 0; e < 4; ++e) {
        acc += 2.f * w[e] * (t[e] * e_w - e_wt) + w[e] * w[e] * d[e] * (1.f / 3.f);
        e_w  += w[e];
        e_wt += w[e] * t[e];
    }

    // ray total via one more DPP scan; lane 63 holds the full sum
    const float tot = wave64_incl_scan(acc);

    // keep the probe loads alive (no arithmetic effect, prevents DCE)
    asm volatile("" :: "v"(pw.x), "v"(pw.y), "v"(pw.z), "v"(pw.w),
                       "v"(pt.x), "v"(pt.y), "v"(pt.z), "v"(pt.w),
                       "v"(pd.x), "v"(pd.y), "v"(pd.z), "v"(pd.w));

    if (lane == 63)
        out[3 * N_RAYS + out_ray] = LAMBDA_DISTORTION * tot;
}

extern "C" void kernel_launch(void* const* d_in, const int* in_sizes, int n_in,
                              void* d_out, int out_size, void* d_ws, size_t ws_size,
                              hipStream_t stream) {
    const float* rgb_coarse   = (const float*)d_in[0];
    const float* rgb_fine     = (const float*)d_in[1];
    const float* rgb_target   = (const float*)d_in[2];
    const float* depth        = (const float*)d_in[3];
    const float* depth_target = (const float*)d_in[4];
    const float* opacity      = (const float*)d_in[5];
    const float* ws           = (const float*)d_in[6];
    const float* deltas       = (const float*)d_in[7];
    const float* ts           = (const float*)d_in[8];
    const int*   rays_a       = (const int*)d_in[9];
    float* out = (float*)d_out;

    fused_kernel<<<NB_PERRAY + NB_DIST, 256, 0, stream>>>(
        rgb_coarse, rgb_fine, rgb_target, depth, depth_target, opacity,
        ws, deltas, ts, rays_a, out);
}

// Round 2
// 165.806 us; speedup vs baseline: 1.1338x; 1.1338x over previous
//
#include <hip/hip_runtime.h>
#include <math.h>

#define N_RAYS 65536
#define LAMBDA_OPACITY 0.001f
#define LAMBDA_DISTORTION 0.001f

// native clang vector type — accepted by __builtin_nontemporal_load
typedef float f32x4 __attribute__((ext_vector_type(4)));

#define NB_PERRAY (N_RAYS / 256)   // 256 perray blocks, dispatched first
#define NB_DIST   (N_RAYS / 4)     // 16384 distortion blocks (4 waves, 1 ray/wave)

// ---------------------------------------------------------------------------
// R12 = R10 restored (probe removed).
// R11 probe measurement established the roofline case:
//   - FETCH_SIZE ~= 141 MB == compulsory input traffic, zero over-fetch
//     (probe's 151 MB re-read was fully L3-absorbed: 137 MB working set
//      < 256 MiB Infinity Cache).
//   - Base kernel K ~= 27 us vs 25 us floor (157 MB @ 6.3 TB/s) ->
//     ~92% of the measured copy-BW ceiling. Memory-bound, saturated.
//   - Remaining 138 us of the benched 165.6 us is harness re-poison fills
//     (256 MiB fillBufferAligned dispatches), outside kernel control.
// ---------------------------------------------------------------------------

// DPP wave64 inclusive-add scan (canonical gfx9 sequence, all-VALU) —
// verified R5/R7/R10.
template <int CTRL, int ROW_MASK>
__device__ __forceinline__ float dpp_add(float x) {
    int s = __builtin_amdgcn_update_dpp(0, __float_as_int(x),
                                        CTRL, ROW_MASK, 0xf, false);
    return x + __int_as_float(s);
}

__device__ __forceinline__ float wave64_incl_scan(float x) {
    x = dpp_add<0x111, 0xf>(x);  // row_shr:1
    x = dpp_add<0x112, 0xf>(x);  // row_shr:2
    x = dpp_add<0x114, 0xf>(x);  // row_shr:4
    x = dpp_add<0x118, 0xf>(x);  // row_shr:8
    x = dpp_add<0x142, 0xa>(x);  // row_bcast:15 -> rows 1,3
    x = dpp_add<0x143, 0xc>(x);  // row_bcast:31 -> rows 2,3
    return x;
}

// ---------------------------------------------------------------------------
// Fused kernel. Blocks [0, NB_PERRAY) do the cheap per-ray terms (dispatched
// first -> fully hidden under distortion). Blocks [NB_PERRAY, +NB_DIST) run
// the R10-winning distortion path: one wave per ray, speculative nt loads
// concurrent with the meta load, DPP scans, lane-63 store.
// ---------------------------------------------------------------------------
__global__ __launch_bounds__(256)
void fused_kernel(
    const float* __restrict__ rgb_coarse,
    const float* __restrict__ rgb_fine,
    const float* __restrict__ rgb_target,
    const float* __restrict__ depth,
    const float* __restrict__ depth_target,
    const float* __restrict__ opacity,
    const float* __restrict__ ws,
    const float* __restrict__ deltas,
    const float* __restrict__ ts,
    const int*   __restrict__ rays_a,
    float* __restrict__ out)
{
    if (blockIdx.x < NB_PERRAY) {
        // ---------------- per-ray cheap terms ----------------
        const int r = blockIdx.x * 256 + threadIdx.x;

        const float rt0 = __builtin_nontemporal_load(rgb_target + r * 3 + 0);
        const float rt1 = __builtin_nontemporal_load(rgb_target + r * 3 + 1);
        const float rt2 = __builtin_nontemporal_load(rgb_target + r * 3 + 2);
        const float c0 = __builtin_nontemporal_load(rgb_coarse + r * 3 + 0) - rt0;
        const float c1 = __builtin_nontemporal_load(rgb_coarse + r * 3 + 1) - rt1;
        const float c2 = __builtin_nontemporal_load(rgb_coarse + r * 3 + 2) - rt2;
        const float f0 = __builtin_nontemporal_load(rgb_fine + r * 3 + 0) - rt0;
        const float f1 = __builtin_nontemporal_load(rgb_fine + r * 3 + 1) - rt1;
        const float f2 = __builtin_nontemporal_load(rgb_fine + r * 3 + 2) - rt2;

        out[r] = (c0 * c0 + c1 * c1 + c2 * c2) * (1.f / 3.f)
               + (f0 * f0 + f1 * f1 + f2 * f2) * (1.f / 3.f);

        out[N_RAYS + r] = fabsf(__builtin_nontemporal_load(depth + r)
                              - __builtin_nontemporal_load(depth_target + r));

        const float o = __builtin_nontemporal_load(opacity + r) + 1e-10f;
        out[2 * N_RAYS + r] = LAMBDA_OPACITY * (-o * logf(o));
        return;
    }

    // ---------------- distortion (R10 winner) ----------------
    const int lane = threadIdx.x & 63;
    const int ray  = (blockIdx.x - NB_PERRAY) * 4 + (threadIdx.x >> 6);

    // speculative nontemporal data loads (identity layout)
    f32x4 vw = {0.f, 0.f, 0.f, 0.f};
    f32x4 vt = {0.f, 0.f, 0.f, 0.f};
    f32x4 vd = {0.f, 0.f, 0.f, 0.f};
    if (lane < 48) {
        const int sp = 192 * ray + 4 * lane;
        vw = __builtin_nontemporal_load((const f32x4*)(ws     + sp));
        vt = __builtin_nontemporal_load((const f32x4*)(ts     + sp));
        vd = __builtin_nontemporal_load((const f32x4*)(deltas + sp));
    }

    // meta load, independent of the data loads -> same round trip
    const int out_ray = rays_a[ray * 3 + 0];
    const int start   = rays_a[ray * 3 + 1];
    const int count   = rays_a[ray * 3 + 2];

    __builtin_amdgcn_sched_barrier(0);

    float w[4] = {0.f, 0.f, 0.f, 0.f};
    float t[4] = {0.f, 0.f, 0.f, 0.f};
    float d[4] = {0.f, 0.f, 0.f, 0.f};

    if (start == 192 * ray && count == 192) {
        if (lane < 48) {
            w[0]=vw.x; w[1]=vw.y; w[2]=vw.z; w[3]=vw.w;
            t[0]=vt.x; t[1]=vt.y; t[2]=vt.z; t[3]=vt.w;
            d[0]=vd.x; d[1]=vd.y; d[2]=vd.z; d[3]=vd.w;
        }
    } else {
        // generic fallback: any start/count, guarded scalar loads
        #pragma unroll
        for (int e = 0; e < 4; ++e) {
            const int p  = 4 * lane + e;
            const bool ok = p < count;
            w[e] = ok ? ws[start + p]     : 0.f;
            t[e] = ok ? ts[start + p]     : 0.f;
            d[e] = ok ? deltas[start + p] : 0.f;
        }
    }

    // per-lane quad totals
    const float wt0 = w[0] * t[0], wt1 = w[1] * t[1];
    const float wt2 = w[2] * t[2], wt3 = w[3] * t[3];
    const float lw  = (w[0] + w[1]) + (w[2] + w[3]);
    const float lwt = (wt0 + wt1) + (wt2 + wt3);

    // DPP inclusive scans over quad totals (two independent chains)
    const float iw  = wave64_incl_scan(lw);
    const float iwt = wave64_incl_scan(lwt);

    // exclusive base for this quad
    float e_w  = iw  - lw;
    float e_wt = iwt - lwt;

    // lane-local sequential exclusive accumulation over the 4 samples
    float acc = 0.f;
    #pragma unroll
    for (int e = 0; e < 4; ++e) {
        acc += 2.f * w[e] * (t[e] * e_w - e_wt) + w[e] * w[e] * d[e] * (1.f / 3.f);
        e_w  += w[e];
        e_wt += w[e] * t[e];
    }

    // ray total via one more DPP scan; lane 63 holds the full sum
    const float tot = wave64_incl_scan(acc);
    if (lane == 63)
        out[3 * N_RAYS + out_ray] = LAMBDA_DISTORTION * tot;
}

extern "C" void kernel_launch(void* const* d_in, const int* in_sizes, int n_in,
                              void* d_out, int out_size, void* d_ws, size_t ws_size,
                              hipStream_t stream) {
    const float* rgb_coarse   = (const float*)d_in[0];
    const float* rgb_fine     = (const float*)d_in[1];
    const float* rgb_target   = (const float*)d_in[2];
    const float* depth        = (const float*)d_in[3];
    const float* depth_target = (const float*)d_in[4];
    const float* opacity      = (const float*)d_in[5];
    const float* ws           = (const float*)d_in[6];
    const float* deltas       = (const float*)d_in[7];
    const float* ts           = (const float*)d_in[8];
    const int*   rays_a       = (const int*)d_in[9];
    float* out = (float*)d_out;

    fused_kernel<<<NB_PERRAY + NB_DIST, 256, 0, stream>>>(
        rgb_coarse, rgb_fine, rgb_target, depth, depth_target, opacity,
        ws, deltas, ts, rays_a, out);
}